// Round 1
// baseline (696.632 us; speedup 1.0000x reference)
//
#include <hip/hip_runtime.h>
#include <cstddef>

constexpr int kDIn  = 1024;
constexpr int kDOut = 1024;
constexpr int kBatch = 32;
constexpr int kE = kDOut + 2 * kDIn + 4;   // 3076
constexpr int kKQRows = 2 * kDIn + 4;      // 2052 rows, starting at e = kDOut
constexpr int kRowsKQ = kBatch * kKQRows;  // 65664
constexpr int kRowsY  = kBatch * kDOut;    // 32768
constexpr int kRowsTotal = kBatch * kE;    // 98432

__device__ __forceinline__ float dot4(float4 a, float4 b) {
    return a.x * b.x + a.y * b.y + a.z * b.z + a.w * b.w;
}

__device__ __forceinline__ float waveReduceSum(float v) {
#pragma unroll
    for (int off = 32; off; off >>= 1) v += __shfl_xor(v, off, 64);
    return v;
}

// ---------------------------------------------------------------------------
// Kernel 1: out[b][e] = w[b,e,:] . x[b,:]   for e in [kDOut, kE)
// One wave per row; ascending row order (k3 consumes in REVERSE for L3 reuse).
// ---------------------------------------------------------------------------
__global__ __launch_bounds__(256) void k_matvec_kq(const float* __restrict__ w,
                                                   const float* __restrict__ x,
                                                   float* __restrict__ outv) {
    const int gw   = (blockIdx.x * 256 + threadIdx.x) >> 6;  // global wave id
    const int lane = threadIdx.x & 63;
    const int b = gw / kKQRows;
    const int e = kDOut + (gw % kKQRows);

    const float4* __restrict__ wr = (const float4*)(w + ((size_t)b * kE + e) * kDIn);
    const float4* __restrict__ xr = (const float4*)(x + (size_t)b * kDIn);

    float acc = 0.f;
#pragma unroll
    for (int it = 0; it < 4; ++it) {
        const int idx = it * 64 + lane;
        acc += dot4(wr[idx], xr[idx]);
    }
    acc = waveReduceSum(acc);
    if (lane == 0) outv[(size_t)b * kE + e] = acc;
}

// ---------------------------------------------------------------------------
// Kernel 2: one block per batch. Computes kphi = softmax(k) and
// dphi = softmax(q) - softmax(k). (qphi never materialized: v - vbar = w.dphi)
// ---------------------------------------------------------------------------
__global__ __launch_bounds__(256) void k_softmax_pair(const float* __restrict__ outv,
                                                      float* __restrict__ kphi,
                                                      float* __restrict__ dphi) {
    const int b   = blockIdx.x;
    const int tid = threadIdx.x;
    const float* __restrict__ base = outv + (size_t)b * kE + kDOut;

    const float4 kv = ((const float4*)base)[tid];
    const float4 qv = ((const float4*)(base + kDIn))[tid];

    // block max of k and q (independent chains, interleaved)
    float mk = fmaxf(fmaxf(kv.x, kv.y), fmaxf(kv.z, kv.w));
    float mq = fmaxf(fmaxf(qv.x, qv.y), fmaxf(qv.z, qv.w));
#pragma unroll
    for (int off = 32; off; off >>= 1) {
        mk = fmaxf(mk, __shfl_xor(mk, off, 64));
        mq = fmaxf(mq, __shfl_xor(mq, off, 64));
    }
    __shared__ float smk[4], smq[4];
    if ((tid & 63) == 0) { smk[tid >> 6] = mk; smq[tid >> 6] = mq; }
    __syncthreads();
    mk = fmaxf(fmaxf(smk[0], smk[1]), fmaxf(smk[2], smk[3]));
    mq = fmaxf(fmaxf(smq[0], smq[1]), fmaxf(smq[2], smq[3]));

    // block sum of exp
    float4 ek, eq;
    ek.x = __expf(kv.x - mk); ek.y = __expf(kv.y - mk);
    ek.z = __expf(kv.z - mk); ek.w = __expf(kv.w - mk);
    eq.x = __expf(qv.x - mq); eq.y = __expf(qv.y - mq);
    eq.z = __expf(qv.z - mq); eq.w = __expf(qv.w - mq);
    float sk = ek.x + ek.y + ek.z + ek.w;
    float sq = eq.x + eq.y + eq.z + eq.w;
#pragma unroll
    for (int off = 32; off; off >>= 1) {
        sk += __shfl_xor(sk, off, 64);
        sq += __shfl_xor(sq, off, 64);
    }
    __shared__ float ssk[4], ssq[4];
    if ((tid & 63) == 0) { ssk[tid >> 6] = sk; ssq[tid >> 6] = sq; }
    __syncthreads();
    sk = ssk[0] + ssk[1] + ssk[2] + ssk[3];
    sq = ssq[0] + ssq[1] + ssq[2] + ssq[3];
    const float ik = 1.f / sk;
    const float iq = 1.f / sq;

    float4 kp, dp;
    kp.x = ek.x * ik; kp.y = ek.y * ik; kp.z = ek.z * ik; kp.w = ek.w * ik;
    dp.x = eq.x * iq - kp.x; dp.y = eq.y * iq - kp.y;
    dp.z = eq.z * iq - kp.z; dp.w = eq.w * iq - kp.w;
    ((float4*)(kphi + (size_t)b * kDIn))[tid] = kp;
    ((float4*)(dphi + (size_t)b * kDIn))[tid] = dp;
}

// ---------------------------------------------------------------------------
// Kernel 3: per row (b, e):
//   acc_d = w_row . dphi            ( = v_e - vbar_e )
//   acc_y = w_row . x               (only for e < kDOut)
//   coef  = sigmoid(beta_e) * acc_d
//   w_out_row = w_row + coef * kphi
// kq rows mapped in REVERSE of k1's order (MRU-first for L3 reuse), then y rows.
// One reduce chain for kq rows, two interleaved chains for y rows.
// ---------------------------------------------------------------------------
__global__ __launch_bounds__(256) void k_update(const float* __restrict__ w,
                                                const float* __restrict__ x,
                                                const float* __restrict__ outv,
                                                const float* __restrict__ kphi,
                                                const float* __restrict__ dphi,
                                                float* __restrict__ y_out,
                                                float* __restrict__ w_out) {
    const int gw   = (blockIdx.x * 256 + threadIdx.x) >> 6;
    const int lane = threadIdx.x & 63;

    int b, e;
    bool isY;
    if (gw < kRowsKQ) {                       // kq rows, reversed (MRU-first)
        const int idx = kRowsKQ - 1 - gw;
        b = idx / kKQRows;
        e = kDOut + (idx % kKQRows);
        isY = false;
    } else {                                  // y rows, ascending
        const int gy = gw - kRowsKQ;
        b = gy >> 10;       // / kDOut
        e = gy & 1023;      // % kDOut
        isY = true;
    }

    const size_t row_off = ((size_t)b * kE + e) * kDIn;
    const float4* __restrict__ wr = (const float4*)(w + row_off);
    const float4* __restrict__ kr = (const float4*)(kphi + (size_t)b * kDIn);
    const float4* __restrict__ dr = (const float4*)(dphi + (size_t)b * kDIn);

    float4 wv[4];
    float acc_d = 0.f, acc_y = 0.f;
    if (isY) {
        const float4* __restrict__ xr = (const float4*)(x + (size_t)b * kDIn);
#pragma unroll
        for (int it = 0; it < 4; ++it) {
            const int idx = it * 64 + lane;
            wv[it] = wr[idx];
            const float4 dv = dr[idx];
            const float4 xv = xr[idx];
            acc_d += dot4(wv[it], dv);
            acc_y += dot4(wv[it], xv);
        }
        // two independent butterflies, interleaved so latencies overlap
#pragma unroll
        for (int off = 32; off; off >>= 1) {
            const float t1 = __shfl_xor(acc_d, off, 64);
            const float t2 = __shfl_xor(acc_y, off, 64);
            acc_d += t1;
            acc_y += t2;
        }
    } else {
#pragma unroll
        for (int it = 0; it < 4; ++it) {
            const int idx = it * 64 + lane;
            wv[it] = wr[idx];
            const float4 dv = dr[idx];
            acc_d += dot4(wv[it], dv);
        }
        acc_d = waveReduceSum(acc_d);
    }

    // beta selection: [0,1024)->b1, [1024,2048)->b2, [2048,3072)->b3, rest->b4
    const int bi = isY ? 0 : (e < kDOut + kDIn) ? 1 : (e < kDOut + 2 * kDIn) ? 2 : 3;
    const float beta = outv[(size_t)b * kE + (kE - 4) + bi];
    const float sig  = 1.f / (1.f + __expf(-beta));
    const float coef = sig * acc_d;

    float4* __restrict__ orow = (float4*)(w_out + row_off);
#pragma unroll
    for (int it = 0; it < 4; ++it) {
        const int idx = it * 64 + lane;
        const float4 kv = kr[idx];          // L1-hot reload; keeps VGPRs low
        float4 o;
        o.x = wv[it].x + coef * kv.x;
        o.y = wv[it].y + coef * kv.y;
        o.z = wv[it].z + coef * kv.z;
        o.w = wv[it].w + coef * kv.w;
        orow[idx] = o;
    }

    if (isY && lane == 0) y_out[(size_t)b * kDOut + e] = acc_y;
}

// ---------------------------------------------------------------------------
extern "C" void kernel_launch(void* const* d_in, const int* in_sizes, int n_in,
                              void* d_out, int out_size, void* d_ws, size_t ws_size,
                              hipStream_t stream) {
    const float* x = (const float*)d_in[0];   // (32, 1024)
    const float* w = (const float*)d_in[1];   // (32, 3076, 1024)

    float* y_out = (float*)d_out;                          // 32*1024
    float* w_out = (float*)d_out + (size_t)kBatch * kDOut; // 32*3076*1024

    // workspace layout (floats)
    float* outv = (float*)d_ws;                              // 32*3076
    float* kphi = outv + (size_t)kBatch * kE;                // 32*1024
    float* dphi = kphi + (size_t)kBatch * kDIn;              // 32*1024

    // Kernel 1: 32 * 2052 rows, 4 rows (waves) per block
    {
        const int blocks = kRowsKQ / 4;  // 16416
        k_matvec_kq<<<blocks, 256, 0, stream>>>(w, x, outv);
    }
    // Kernel 2: one block per batch
    k_softmax_pair<<<kBatch, 256, 0, stream>>>(outv, kphi, dphi);

    // Kernel 3: 32 * 3076 rows, 4 rows per block (kq rows reversed first)
    {
        const int blocks = kRowsTotal / 4;  // 24608
        k_update<<<blocks, 256, 0, stream>>>(w, x, outv, kphi, dphi, y_out, w_out);
    }
}

// Round 3
// 680.950 us; speedup vs baseline: 1.0230x; 1.0230x over previous
//
#include <hip/hip_runtime.h>
#include <cstddef>

constexpr int kDIn  = 1024;
constexpr int kDOut = 1024;
constexpr int kBatch = 32;
constexpr int kE = kDOut + 2 * kDIn + 4;   // 3076
constexpr int kKQRows = 2 * kDIn + 4;      // 2052 rows, starting at e = kDOut
constexpr int kRowsKQ = kBatch * kKQRows;  // 65664
constexpr int kRowsTotal = kBatch * kE;    // 98432

typedef float floatx4 __attribute__((ext_vector_type(4)));  // native vec for nt builtins

__device__ __forceinline__ float dot4(float4 a, float4 b) {
    return a.x * b.x + a.y * b.y + a.z * b.z + a.w * b.w;
}
__device__ __forceinline__ float dot4v(floatx4 a, float4 b) {
    return a.x * b.x + a.y * b.y + a.z * b.z + a.w * b.w;
}

// ---------------------------------------------------------------------------
// Wave64 sum via DPP (pure VALU, no LDS): canonical GCN sequence.
// After this, lane 63 holds the full 64-lane sum; use readlane(63).
// row_shr:N = 0x110|N, row_bcast:15 = 0x142, row_bcast:31 = 0x143.
// bound_ctrl=true -> out-of-row lanes contribute 0.
// ---------------------------------------------------------------------------
__device__ __forceinline__ float dppSumTo63(float v) {
    int t;
    t = __builtin_amdgcn_update_dpp(0, __float_as_int(v), 0x111, 0xf, 0xf, true); v += __int_as_float(t);
    t = __builtin_amdgcn_update_dpp(0, __float_as_int(v), 0x112, 0xf, 0xf, true); v += __int_as_float(t);
    t = __builtin_amdgcn_update_dpp(0, __float_as_int(v), 0x114, 0xf, 0xf, true); v += __int_as_float(t);
    t = __builtin_amdgcn_update_dpp(0, __float_as_int(v), 0x118, 0xf, 0xf, true); v += __int_as_float(t);
    t = __builtin_amdgcn_update_dpp(0, __float_as_int(v), 0x142, 0xa, 0xf, true); v += __int_as_float(t);
    t = __builtin_amdgcn_update_dpp(0, __float_as_int(v), 0x143, 0xc, 0xf, true); v += __int_as_float(t);
    return v;
}

__device__ __forceinline__ float waveBcast63(float v) {
    return __int_as_float(__builtin_amdgcn_readlane(__float_as_int(v), 63));
}

// ---------------------------------------------------------------------------
// Kernel 1: out[b][e] = w[b,e,:] . x[b,:]   for e in [kDOut, kE)
// One wave per row; ascending row order (k3 consumes in REVERSE for L3 reuse).
// ---------------------------------------------------------------------------
__global__ __launch_bounds__(256) void k_matvec_kq(const float* __restrict__ w,
                                                   const float* __restrict__ x,
                                                   float* __restrict__ outv) {
    const int gw   = (blockIdx.x * 256 + threadIdx.x) >> 6;  // global wave id
    const int lane = threadIdx.x & 63;
    const int b = gw / kKQRows;
    const int e = kDOut + (gw % kKQRows);

    const float4* __restrict__ wr = (const float4*)(w + ((size_t)b * kE + e) * kDIn);
    const float4* __restrict__ xr = (const float4*)(x + (size_t)b * kDIn);

    float acc = 0.f;
#pragma unroll
    for (int it = 0; it < 4; ++it) {
        const int idx = it * 64 + lane;
        acc += dot4(wr[idx], xr[idx]);
    }
    acc = waveBcast63(dppSumTo63(acc));
    if (lane == 0) outv[(size_t)b * kE + e] = acc;
}

// ---------------------------------------------------------------------------
// Kernel 2: one block per batch. Computes kphi = softmax(k) and
// dphi = softmax(q) - softmax(k). (qphi never materialized: v - vbar = w.dphi)
// Tiny kernel (32 blocks) — shfl reduce is fine here.
// ---------------------------------------------------------------------------
__global__ __launch_bounds__(256) void k_softmax_pair(const float* __restrict__ outv,
                                                      float* __restrict__ kphi,
                                                      float* __restrict__ dphi) {
    const int b   = blockIdx.x;
    const int tid = threadIdx.x;
    const float* __restrict__ base = outv + (size_t)b * kE + kDOut;

    const float4 kv = ((const float4*)base)[tid];
    const float4 qv = ((const float4*)(base + kDIn))[tid];

    float mk = fmaxf(fmaxf(kv.x, kv.y), fmaxf(kv.z, kv.w));
    float mq = fmaxf(fmaxf(qv.x, qv.y), fmaxf(qv.z, qv.w));
#pragma unroll
    for (int off = 32; off; off >>= 1) {
        mk = fmaxf(mk, __shfl_xor(mk, off, 64));
        mq = fmaxf(mq, __shfl_xor(mq, off, 64));
    }
    __shared__ float smk[4], smq[4];
    if ((tid & 63) == 0) { smk[tid >> 6] = mk; smq[tid >> 6] = mq; }
    __syncthreads();
    mk = fmaxf(fmaxf(smk[0], smk[1]), fmaxf(smk[2], smk[3]));
    mq = fmaxf(fmaxf(smq[0], smq[1]), fmaxf(smq[2], smq[3]));

    float4 ek, eq;
    ek.x = __expf(kv.x - mk); ek.y = __expf(kv.y - mk);
    ek.z = __expf(kv.z - mk); ek.w = __expf(kv.w - mk);
    eq.x = __expf(qv.x - mq); eq.y = __expf(qv.y - mq);
    eq.z = __expf(qv.z - mq); eq.w = __expf(qv.w - mq);
    float sk = ek.x + ek.y + ek.z + ek.w;
    float sq = eq.x + eq.y + eq.z + eq.w;
#pragma unroll
    for (int off = 32; off; off >>= 1) {
        sk += __shfl_xor(sk, off, 64);
        sq += __shfl_xor(sq, off, 64);
    }
    __shared__ float ssk[4], ssq[4];
    if ((tid & 63) == 0) { ssk[tid >> 6] = sk; ssq[tid >> 6] = sq; }
    __syncthreads();
    sk = ssk[0] + ssk[1] + ssk[2] + ssk[3];
    sq = ssq[0] + ssq[1] + ssq[2] + ssq[3];
    const float ik = 1.f / sk;
    const float iq = 1.f / sq;

    float4 kp, dp;
    kp.x = ek.x * ik; kp.y = ek.y * ik; kp.z = ek.z * ik; kp.w = ek.w * ik;
    dp.x = eq.x * iq - kp.x; dp.y = eq.y * iq - kp.y;
    dp.z = eq.z * iq - kp.z; dp.w = eq.w * iq - kp.w;
    ((float4*)(kphi + (size_t)b * kDIn))[tid] = kp;
    ((float4*)(dphi + (size_t)b * kDIn))[tid] = dp;
}

// ---------------------------------------------------------------------------
// Kernel 3: per row (b, e):
//   acc_d = w_row . dphi            ( = v_e - vbar_e )
//   acc_y = w_row . x               (only for e < kDOut)
//   coef  = sigmoid(beta_e) * acc_d
//   w_out_row = w_row + coef * kphi
// kq rows mapped in REVERSE of k1's order (MRU-first L3 reuse): NORMAL loads.
// y rows (never touched by k1): NONTEMPORAL loads (don't evict kq lines).
// All w_out stores NONTEMPORAL (no write-allocate -> preserves L3 for reuse).
// DPP reduce: no LDS ops in the reduction.
// ---------------------------------------------------------------------------
__global__ __launch_bounds__(256) void k_update(const float* __restrict__ w,
                                                const float* __restrict__ x,
                                                const float* __restrict__ outv,
                                                const float* __restrict__ kphi,
                                                const float* __restrict__ dphi,
                                                float* __restrict__ y_out,
                                                float* __restrict__ w_out) {
    const int gw   = (blockIdx.x * 256 + threadIdx.x) >> 6;
    const int lane = threadIdx.x & 63;

    int b, e;
    bool isY;
    if (gw < kRowsKQ) {                       // kq rows, reversed (MRU-first)
        const int idx = kRowsKQ - 1 - gw;
        b = idx / kKQRows;
        e = kDOut + (idx % kKQRows);
        isY = false;
    } else {                                  // y rows, ascending
        const int gy = gw - kRowsKQ;
        b = gy >> 10;       // / kDOut
        e = gy & 1023;      // % kDOut
        isY = true;
    }

    const size_t row_off = ((size_t)b * kE + e) * kDIn;
    const float4*  __restrict__ wr  = (const float4*)(w + row_off);
    const floatx4* __restrict__ wrn = (const floatx4*)(w + row_off);
    const float4*  __restrict__ kr  = (const float4*)(kphi + (size_t)b * kDIn);
    const float4*  __restrict__ dr  = (const float4*)(dphi + (size_t)b * kDIn);

    floatx4 wv[4];
    float acc_d = 0.f, acc_y = 0.f;
    if (isY) {
        const float4* __restrict__ xr = (const float4*)(x + (size_t)b * kDIn);
#pragma unroll
        for (int it = 0; it < 4; ++it) {
            const int idx = it * 64 + lane;
            wv[it] = __builtin_nontemporal_load(&wrn[idx]);   // single-use rows
            const float4 dv = dr[idx];
            const float4 xv = xr[idx];
            acc_d += dot4v(wv[it], dv);
            acc_y += dot4v(wv[it], xv);
        }
        // two independent DPP chains (VALU-only, latencies overlap)
        acc_d = dppSumTo63(acc_d);
        acc_y = dppSumTo63(acc_y);
        acc_d = waveBcast63(acc_d);
        acc_y = waveBcast63(acc_y);
    } else {
#pragma unroll
        for (int it = 0; it < 4; ++it) {
            const int idx = it * 64 + lane;
            const float4 wl = wr[idx];                        // want L3 hits from k1
            wv[it].x = wl.x; wv[it].y = wl.y; wv[it].z = wl.z; wv[it].w = wl.w;
            const float4 dv = dr[idx];
            acc_d += dot4v(wv[it], dv);
        }
        acc_d = waveBcast63(dppSumTo63(acc_d));
    }

    // beta selection: [0,1024)->b1, [1024,2048)->b2, [2048,3072)->b3, rest->b4
    const int bi = isY ? 0 : (e < kDOut + kDIn) ? 1 : (e < kDOut + 2 * kDIn) ? 2 : 3;
    const float beta = outv[(size_t)b * kE + (kE - 4) + bi];
    const float sig  = 1.f / (1.f + __expf(-beta));
    const float coef = sig * acc_d;

    floatx4* __restrict__ orow = (floatx4*)(w_out + row_off);
#pragma unroll
    for (int it = 0; it < 4; ++it) {
        const int idx = it * 64 + lane;
        const float4 kv = kr[idx];          // L1-hot reload; keeps VGPRs low
        floatx4 o;
        o.x = wv[it].x + coef * kv.x;
        o.y = wv[it].y + coef * kv.y;
        o.z = wv[it].z + coef * kv.z;
        o.w = wv[it].w + coef * kv.w;
        __builtin_nontemporal_store(o, &orow[idx]);   // no write-allocate
    }

    if (isY && lane == 0) y_out[(size_t)b * kDOut + e] = acc_y;
}

// ---------------------------------------------------------------------------
extern "C" void kernel_launch(void* const* d_in, const int* in_sizes, int n_in,
                              void* d_out, int out_size, void* d_ws, size_t ws_size,
                              hipStream_t stream) {
    const float* x = (const float*)d_in[0];   // (32, 1024)
    const float* w = (const float*)d_in[1];   // (32, 3076, 1024)

    float* y_out = (float*)d_out;                          // 32*1024
    float* w_out = (float*)d_out + (size_t)kBatch * kDOut; // 32*3076*1024

    // workspace layout (floats)
    float* outv = (float*)d_ws;                              // 32*3076
    float* kphi = outv + (size_t)kBatch * kE;                // 32*1024
    float* dphi = kphi + (size_t)kBatch * kDIn;              // 32*1024

    // Kernel 1: 32 * 2052 rows, 4 rows (waves) per block
    {
        const int blocks = kRowsKQ / 4;  // 16416
        k_matvec_kq<<<blocks, 256, 0, stream>>>(w, x, outv);
    }
    // Kernel 2: one block per batch
    k_softmax_pair<<<kBatch, 256, 0, stream>>>(outv, kphi, dphi);

    // Kernel 3: 32 * 3076 rows, 4 rows per block (kq rows reversed first)
    {
        const int blocks = kRowsTotal / 4;  // 24608
        k_update<<<blocks, 256, 0, stream>>>(w, x, outv, kphi, dphi, y_out, w_out);
    }
}